// Round 1
// baseline (288.776 us; speedup 1.0000x reference)
//
#include <hip/hip_runtime.h>

// Shapes fixed by the reference.
#define N_  64
#define T_  4096
#define D_  128
#define CH_ 32            // t-chunks for context partials
#define TC_ (T_ / CH_)    // 128 t per chunk

// ---------------------------------------------------------------------------
// Kernel 1: energy[n,t] = sum_d key[t,n,d] * query[n,d]
// One wave per (n,t) row: 64 lanes x float2 = 512B coalesced per load.
// grid = N * (T/64) blocks of 256 (4 waves); each wave does 16 t's.
// ---------------------------------------------------------------------------
__global__ __launch_bounds__(256) void energy_kernel(const float* __restrict__ key,
                                                     const float* __restrict__ query,
                                                     float* __restrict__ energy) {
    const int lane = threadIdx.x & 63;
    const int wave = threadIdx.x >> 6;
    const int n  = blockIdx.x >> 6;                       // T/64 = 64 tiles per n
    const int t0 = ((blockIdx.x & 63) << 6) + (wave << 4);

    const float2 q = *reinterpret_cast<const float2*>(query + n * D_ + lane * 2);

    #pragma unroll 4
    for (int i = 0; i < 16; ++i) {
        const int t = t0 + i;
        const float2 k2 = *reinterpret_cast<const float2*>(
            key + ((size_t)t * N_ + n) * D_ + lane * 2);
        float p = k2.x * q.x + k2.y * q.y;
        #pragma unroll
        for (int off = 32; off; off >>= 1) p += __shfl_xor(p, off, 64);
        if (lane == 0) energy[n * T_ + t] = p;
    }
}

// ---------------------------------------------------------------------------
// Kernel 2: score = softmax(mask * energy) over t, in-place on the energy
// buffer; also writes the mask output. One block (256 thr) per n.
// Masked positions keep value 0 (multiplicative mask, NOT -inf).
// ---------------------------------------------------------------------------
__global__ __launch_bounds__(256) void softmax_kernel(float* __restrict__ energy_score,
                                                      const int* __restrict__ slen,
                                                      float* __restrict__ mask_out) {
    const int n   = blockIdx.x;
    const int len = slen[n];
    const int tid = threadIdx.x;
    const int lane = tid & 63;
    const int wv   = tid >> 6;

    float ev[T_ / 256];
    #pragma unroll
    for (int i = 0; i < T_ / 256; ++i) {
        const int t = tid + i * 256;
        const float e = energy_score[n * T_ + t];
        ev[i] = (t < len) ? e : 0.f;
    }

    // ---- block max ----
    float m = -3.4e38f;
    #pragma unroll
    for (int i = 0; i < T_ / 256; ++i) m = fmaxf(m, ev[i]);
    #pragma unroll
    for (int off = 32; off; off >>= 1) m = fmaxf(m, __shfl_xor(m, off, 64));
    __shared__ float wred[4];
    if (lane == 0) wred[wv] = m;
    __syncthreads();
    m = fmaxf(fmaxf(wred[0], wred[1]), fmaxf(wred[2], wred[3]));
    __syncthreads();

    // ---- block sum of exp ----
    float s = 0.f;
    #pragma unroll
    for (int i = 0; i < T_ / 256; ++i) s += __expf(ev[i] - m);
    #pragma unroll
    for (int off = 32; off; off >>= 1) s += __shfl_xor(s, off, 64);
    if (lane == 0) wred[wv] = s;
    __syncthreads();
    s = wred[0] + wred[1] + wred[2] + wred[3];
    const float inv = 1.f / s;

    // ---- write score (in place) + mask output ----
    #pragma unroll
    for (int i = 0; i < T_ / 256; ++i) {
        const int t = tid + i * 256;
        energy_score[n * T_ + t] = __expf(ev[i] - m) * inv;
        mask_out[n * T_ + t] = (t < len) ? 1.f : 0.f;
    }
}

// ---------------------------------------------------------------------------
// Kernel 3: partial context. grid = N * CH blocks of 256.
// Block (n, c): part[n,c,v] = sum_{t in chunk c} score[n,t] * value[t,n,v].
// 4 waves each own a t-phase; each wave reads one 512B value row per iter.
// ---------------------------------------------------------------------------
__global__ __launch_bounds__(256) void ctx_partial_kernel(const float* __restrict__ value,
                                                          const float* __restrict__ score,
                                                          float* __restrict__ part) {
    const int n = blockIdx.x / CH_;
    const int c = blockIdx.x % CH_;
    const int lane = threadIdx.x & 63;
    const int g    = threadIdx.x >> 6;      // 0..3
    const int tbase = c * TC_;

    float2 acc = make_float2(0.f, 0.f);
    for (int i = g; i < TC_; i += 4) {
        const int t = tbase + i;
        const float sc = score[n * T_ + t];
        const float2 v2 = *reinterpret_cast<const float2*>(
            value + ((size_t)t * N_ + n) * D_ + lane * 2);
        acc.x += sc * v2.x;
        acc.y += sc * v2.y;
    }

    __shared__ float2 red[4][64];
    red[g][lane] = acc;
    __syncthreads();
    if (g == 0) {
        const float2 a = red[0][lane], b = red[1][lane];
        const float2 cc = red[2][lane], d = red[3][lane];
        float2 r;
        r.x = (a.x + b.x) + (cc.x + d.x);
        r.y = (a.y + b.y) + (cc.y + d.y);
        *reinterpret_cast<float2*>(part + ((size_t)(n * CH_ + c)) * D_ + lane * 2) = r;
    }
}

// ---------------------------------------------------------------------------
// Kernel 4: context[n,v] = sum_c part[n,c,v]. grid = N blocks of 128.
// ---------------------------------------------------------------------------
__global__ __launch_bounds__(128) void ctx_reduce_kernel(const float* __restrict__ part,
                                                         float* __restrict__ ctx_out) {
    const int n = blockIdx.x;
    const int v = threadIdx.x;
    float acc = 0.f;
    #pragma unroll 8
    for (int c = 0; c < CH_; ++c) acc += part[((size_t)(n * CH_ + c)) * D_ + v];
    ctx_out[n * D_ + v] = acc;
}

// ---------------------------------------------------------------------------
extern "C" void kernel_launch(void* const* d_in, const int* in_sizes, int n_in,
                              void* d_out, int out_size, void* d_ws, size_t ws_size,
                              hipStream_t stream) {
    const float* query = (const float*)d_in[0];   // (N, D)
    const float* key   = (const float*)d_in[1];   // (T, N, D)
    const float* value = (const float*)d_in[2];   // (T, N, D)
    const int*   slen  = (const int*)d_in[3];     // (N,)

    float* out      = (float*)d_out;
    float* ctx_out  = out;                // N*D floats
    float* mask_out = out + N_ * D_;      // N*T floats

    float* energy_score = (float*)d_ws;               // N*T floats (energy, then score in-place)
    float* partials     = energy_score + N_ * T_;     // N*CH*D floats

    energy_kernel<<<N_ * (T_ / 64), 256, 0, stream>>>(key, query, energy_score);
    softmax_kernel<<<N_, 256, 0, stream>>>(energy_score, slen, mask_out);
    ctx_partial_kernel<<<N_ * CH_, 256, 0, stream>>>(value, energy_score, partials);
    ctx_reduce_kernel<<<N_, 128, 0, stream>>>(partials, ctx_out);
}

// Round 6
// 275.323 us; speedup vs baseline: 1.0489x; 1.0489x over previous
//
#include <hip/hip_runtime.h>

// Shapes fixed by the reference.
#define N_  64
#define T_  4096
#define D_  128
#define CH_ 32            // t-chunks per n
#define TC_ (T_ / CH_)    // 128 t per chunk

// ---------------------------------------------------------------------------
// Kernel A: fused per-chunk flash pass. Block (n,c), 256 threads (4 waves).
//   phase 1: energies e_t = <key[t,n,:], q[n,:]> for the 128 t's in chunk,
//            masked (t>=len -> 0, multiplicative-mask semantics).
//   block max m_c, p_t = exp(e_t - m_c), s_c = sum p_t.
//   phase 2: acc_c[v] = sum_t p_t * value[t,n,v].
// float4 per lane: half-wave 0 (lanes 0-31) covers row t, half-wave 1 covers
// row t+1 -> one wave load = 1KB over two rows; 5-shfl half-wave dot reduce.
// ---------------------------------------------------------------------------
__global__ __launch_bounds__(256) void chunk_kernel(
    const float* __restrict__ key, const float* __restrict__ value,
    const float* __restrict__ query, const int* __restrict__ slen,
    float* __restrict__ mask_out, float* __restrict__ m_ws,
    float* __restrict__ s_ws, float* __restrict__ acc_ws)
{
    const int n    = blockIdx.x / CH_;
    const int c    = blockIdx.x % CH_;
    const int tid  = threadIdx.x;
    const int lane = tid & 63;
    const int wv   = tid >> 6;        // 0..3
    const int half = lane >> 5;       // 0 or 1 (which t of the pair)
    const int hl   = lane & 31;       // lane within half-wave
    const int tbase = c * TC_;
    const int len   = slen[n];

    __shared__ float  ep[TC_];        // energies, then p values (in place)
    __shared__ float  wred[8];
    __shared__ float4 red[4][32];

    const float4 q4 = *reinterpret_cast<const float4*>(query + n * D_ + hl * 4);

    // ---- phase 1: energies ----
    #pragma unroll 4
    for (int i = 0; i < 16; ++i) {
        const int lt = wv * 32 + i * 2 + half;     // local t in [0,128)
        const int t  = tbase + lt;
        const float4 k4 = *reinterpret_cast<const float4*>(
            key + ((size_t)t * N_ + n) * D_ + hl * 4);
        float p = k4.x * q4.x + k4.y * q4.y + k4.z * q4.z + k4.w * q4.w;
        #pragma unroll
        for (int off = 16; off; off >>= 1) p += __shfl_xor(p, off, 64);
        if (hl == 0) ep[lt] = (t < len) ? p : 0.f;  // multiplicative mask -> 0
    }
    __syncthreads();

    // ---- chunk max ----
    const float ev = (tid < TC_) ? ep[tid] : -3.4e38f;
    float m = ev;
    #pragma unroll
    for (int off = 32; off; off >>= 1) m = fmaxf(m, __shfl_xor(m, off, 64));
    if (lane == 0) wred[wv] = m;
    __syncthreads();
    m = fmaxf(fmaxf(wred[0], wred[1]), fmaxf(wred[2], wred[3]));

    // ---- p = exp(e - m), chunk sum; also emit mask output ----
    float sp = 0.f;
    if (tid < TC_) {
        const float p = __expf(ev - m);
        ep[tid] = p;                   // own slot; published by barrier below
        sp = p;
        mask_out[n * T_ + tbase + tid] = (tbase + tid < len) ? 1.f : 0.f;
    }
    #pragma unroll
    for (int off = 32; off; off >>= 1) sp += __shfl_xor(sp, off, 64);
    if (lane == 0) wred[4 + wv] = sp;
    __syncthreads();                   // publishes ep[] (p values) and wred[4..7]
    if (tid == 0) {
        m_ws[n * CH_ + c] = m;
        s_ws[n * CH_ + c] = wred[4] + wred[5] + wred[6] + wred[7];
    }

    // ---- phase 2: weighted V accumulation ----
    float4 acc = make_float4(0.f, 0.f, 0.f, 0.f);
    #pragma unroll 4
    for (int i = 0; i < 16; ++i) {
        const int lt = wv * 32 + i * 2 + half;
        const int t  = tbase + lt;
        const float4 v4 = *reinterpret_cast<const float4*>(
            value + ((size_t)t * N_ + n) * D_ + hl * 4);
        const float pv = ep[lt];       // 2-way broadcast, conflict-free
        acc.x += pv * v4.x; acc.y += pv * v4.y;
        acc.z += pv * v4.z; acc.w += pv * v4.w;
    }
    // combine the two halves (both hold the same d-range for t and t+1)
    acc.x += __shfl_xor(acc.x, 32, 64);
    acc.y += __shfl_xor(acc.y, 32, 64);
    acc.z += __shfl_xor(acc.z, 32, 64);
    acc.w += __shfl_xor(acc.w, 32, 64);
    if (half == 0) red[wv][hl] = acc;
    __syncthreads();
    if (tid < 32) {
        const float4 a = red[0][tid], b = red[1][tid];
        const float4 e = red[2][tid], d = red[3][tid];
        float4 r;
        r.x = (a.x + b.x) + (e.x + d.x);
        r.y = (a.y + b.y) + (e.y + d.y);
        r.z = (a.z + b.z) + (e.z + d.z);
        r.w = (a.w + b.w) + (e.w + d.w);
        *reinterpret_cast<float4*>(acc_ws + ((size_t)(n * CH_ + c)) * D_ + tid * 4) = r;
    }
}

// ---------------------------------------------------------------------------
// Kernel B: combine 32 chunk partials per n.
//   M = max_c m_c;  S = sum_c s_c*exp(m_c-M);  ctx = sum_c exp(m_c-M)*acc_c / S
// 64 blocks x 64 threads; lane v handles d-range [2v, 2v+2).
// ---------------------------------------------------------------------------
__global__ __launch_bounds__(64) void finalize_kernel(
    const float* __restrict__ m_ws, const float* __restrict__ s_ws,
    const float* __restrict__ acc_ws, float* __restrict__ ctx)
{
    const int n    = blockIdx.x;
    const int lane = threadIdx.x;

    const float mc = (lane < CH_) ? m_ws[n * CH_ + lane] : -3.4e38f;
    float M = mc;
    #pragma unroll
    for (int off = 32; off; off >>= 1) M = fmaxf(M, __shfl_xor(M, off, 64));

    const float ew = (lane < CH_) ? __expf(mc - M) : 0.f;
    float S = (lane < CH_) ? s_ws[n * CH_ + lane] * ew : 0.f;
    #pragma unroll
    for (int off = 32; off; off >>= 1) S += __shfl_xor(S, off, 64);

    float2 r = make_float2(0.f, 0.f);
    #pragma unroll 8
    for (int c = 0; c < CH_; ++c) {
        const float w = __shfl(ew, c, 64);   // broadcast chunk c's weight
        const float2 a = *reinterpret_cast<const float2*>(
            acc_ws + ((size_t)(n * CH_ + c)) * D_ + lane * 2);
        r.x += w * a.x; r.y += w * a.y;
    }
    const float invS = 1.f / S;
    *reinterpret_cast<float2*>(ctx + n * D_ + lane * 2) =
        make_float2(r.x * invS, r.y * invS);
}

// ---------------------------------------------------------------------------
extern "C" void kernel_launch(void* const* d_in, const int* in_sizes, int n_in,
                              void* d_out, int out_size, void* d_ws, size_t ws_size,
                              hipStream_t stream) {
    const float* query = (const float*)d_in[0];   // (N, D)
    const float* key   = (const float*)d_in[1];   // (T, N, D)
    const float* value = (const float*)d_in[2];   // (T, N, D)
    const int*   slen  = (const int*)d_in[3];     // (N,)

    float* out      = (float*)d_out;
    float* ctx_out  = out;                // N*D floats
    float* mask_out = out + N_ * D_;      // N*T floats

    float* m_ws   = (float*)d_ws;                 // N*CH
    float* s_ws   = m_ws + N_ * CH_;              // N*CH
    float* acc_ws = s_ws + N_ * CH_;              // N*CH*D

    chunk_kernel<<<N_ * CH_, 256, 0, stream>>>(key, value, query, slen,
                                               mask_out, m_ws, s_ws, acc_ws);
    finalize_kernel<<<N_, 64, 0, stream>>>(m_ws, s_ws, acc_ws, ctx_out);
}